// Round 6
// baseline (112.713 us; speedup 1.0000x reference)
//
#include <hip/hip_runtime.h>
#include <stdint.h>

// Problem constants: B=8, P=4096, N=1024, H=W=1024, labels 0..1024
#define PPTS 4096
#define NGT  1024
#define HH   1024
#define WW   1024
#define EVPOOL_CAP 3072   // LDS event-slot pool; first-dump events ~1900 < cap
#define BGCAP 160         // max bg steps (E[m] ~65)
#define RB 12             // register-bucket cap in 1a (12 = proven scratch-free; 16 spills)

// workspace layout: spill u16[8][2048] only (labels/hist now computed in-kernel)
#define SPILL_CAP  2048
#define WS_NEED    (8 * SPILL_CAP * 2)

typedef unsigned long long u64;

// squared distance, add-form (NOT fma) to bit-match reference dx*dx + dy*dy;
// sqrt is applied once to WINNERS only (sqrt_rn is monotone -> same argmin).
__device__ __forceinline__ float pdist2(float vx, float vy, float ux, float uy) {
    float dx = __fsub_rn(vx, ux);
    float dy = __fsub_rn(vy, uy);
    return __fadd_rn(__fmul_rn(dx, dx), __fmul_rn(dy, dy));
}

// Single fused kernel: one block per batch — labels computed inline (mono
// path, gathers issued at kernel start and overlapped with LDS init), then
// r12 structure + grid beta + commit-and-fix 2c.
__global__ __launch_bounds__(1024) void matcher_kernel(
    const float* __restrict__ pred,    // [B,P,2]
    const float* __restrict__ coords,  // [B,N,2]
    const int*   __restrict__ keys,    // [B,N]
    const int*   __restrict__ masks,   // [B,H,W]
    float* __restrict__ out,           // [B*N src][B*N tgt][B total]
    unsigned short* __restrict__ spill, int spillCap, int B)
{
    __shared__ __align__(16) char regU[32768];          // bucketC f2[4096] (bg0 + staged ev)
    __shared__ __align__(8)  char regE[8192];           // ldsEnt u16[4096]
    __shared__ __align__(8)  char regB[8200];           // bEnd+occA -> specWin u64[BGCAP]
    __shared__ __align__(8)  char regP[2 * EVPOOL_CAP]; // firstOcc i32 -> evPool u16
    __shared__ __align__(4)  char regS[384];            // present u32[33] -> bgListSh u16[BGCAP]
    __shared__ __align__(8)  char regT[2048];           // bSt u16[1024] -> vSteps f2[BGCAP]
    __shared__ u64            wScr64[16];
    __shared__ u64            sTot;
    __shared__ unsigned short evAx[1024];
    __shared__ unsigned short occList[NGT];
    __shared__ short          matchU[NGT];
    __shared__ unsigned       bgbits[PPTS / 32];        // consumed-winner bitmap
    __shared__ int            scal[4];                  // 0:bgCnt 3:earliest-invalid
    __shared__ float2         vLds[NGT];                // V staged in LDS (1a gathers)
    // spatial grid (beta): 32x32 cells over [0,1]^2 — dedicated storage
    __shared__ unsigned       cellCnt[1024];            // counts -> excl scan -> ends
    __shared__ unsigned short cellOf[PPTS];             // cell of staged entry i
    __shared__ unsigned short gIdx[PPTS];               // staged-entry index (prefix filter)
    __shared__ unsigned short gP[PPTS];                 // point id
    __shared__ __align__(16) float2 gC[PPTS];           // coords

    float2*         bucketC  = (float2*)regU;
    unsigned short* ldsEnt   = (unsigned short*)regE;
    int*            bEnd     = (int*)regB;
    int*            occA     = ((int*)regB) + 1025;
    u64*            specWin  = (u64*)regB;
    int*            firstOcc = (int*)regP;
    unsigned short* evPool   = (unsigned short*)regP;
    unsigned*       present  = (unsigned*)regS;
    unsigned short* bgListSh = (unsigned short*)regS;
    unsigned short* bSt      = (unsigned short*)regT;   // dead after 1a
    float2*         vSteps   = (float2*)regT;           // alias: written at compaction
    int*   wScrI = (int*)wScr64;
    float* wScrF = (float*)wScr64;

    const int b = blockIdx.x;
    const int t = threadIdx.x;
    const int lane = t & 63, wv = t >> 6;
    const float* Ub = pred   + (size_t)b * PPTS * 2;
    const float2* Ub2 = (const float2*)Ub;
    const float* Vb = coords + (size_t)b * NGT * 2;
    const float2* Vb2 = (const float2*)Vb;
    const int*   Kb = keys   + (size_t)b * NGT;
    unsigned short* evSpillB = spill + (size_t)b * SPILL_CAP;

    // ---- A: issue all global loads first (gathers overlap LDS init) ----
    int lab[4]; float2 up[4];
    #pragma unroll
    for (int i = 0; i < 4; i++) up[i] = Ub2[t + (i << 10)];
    const int k1v = Kb[t];                       // raw key (label-1)
    const float2 vMe = Vb2[t];                   // coalesced; reused for vSteps
    const int* Mb = masks + (size_t)b * HH * WW;
    #pragma unroll
    for (int i = 0; i < 4; i++) {                // mask gathers — in flight until B
        int xi = (int)rintf(__fmul_rn(up[i].x, 1024.0f));   // rintf == jnp.round
        int yi = (int)rintf(__fmul_rn(up[i].y, 1024.0f));
        xi = min(max(xi, 0), HH - 1);
        yi = min(max(yi, 0), WW - 1);
        lab[i] = Mb[xi * WW + yi];
    }
    const int k1 = k1v + 1;                      // label of step j=t, in [1,1024]
    // LDS init (independent of in-flight gathers)
    if (t < PPTS / 32) bgbits[t] = 0;
    if (t == 0) scal[0] = 0;
    cellCnt[t] = 0;                              // grid counts (filled at D/staging)
    vLds[t] = vMe;                               // stage V in LDS for 1a gathers
    occA[t] = 0; firstOcc[t] = 0x7FFFFFFF;
    bEnd[t] = 0;
    if (t == 0) { occA[1024] = 0; firstOcc[1024] = 0x7FFFFFFF; bEnd[1024] = 0; }
    if (t < 33) present[t] = 0;
    __syncthreads();

    // ---- B: histogram + key-side stats (LDS atomics) ----
    atomicOr(&present[k1 >> 5], 1u << (k1 & 31));
    atomicAdd(&occA[k1], 1);
    atomicMin(&firstOcc[k1], t);
    #pragma unroll
    for (int i = 0; i < 4; i++) atomicAdd(&bEnd[lab[i]], 1);
    __syncthreads();

    // ---- C: quad-packed exclusive scan (bg<<48 | pr<<32 | ev<<16 | occ) ----
    {
        int c0 = bEnd[t], o0 = occA[t];
        bool pr0 = (present[t >> 5] >> (t & 31)) & 1u;
        int bCnt = bEnd[k1];
        int fo   = firstOcc[k1];
        int evc  = (fo == t && bCnt > 0) ? (bCnt - 1) : 0;
        u64 myv = (pr0 ? ((u64)(unsigned)c0 << 32) : ((u64)(unsigned)c0 << 48))
                  | ((u64)(unsigned)evc << 16) | (u64)(unsigned)o0;
        u64 add1 = 0; bool pr1 = false;
        if (t == 1023) {                          // fold label 1024 (no step 1024)
            int c1 = bEnd[1024], o1 = occA[1024];
            pr1 = present[32] & 1u;
            add1 = (pr1 ? ((u64)(unsigned)c1 << 32) : ((u64)(unsigned)c1 << 48))
                   | (u64)(unsigned)o1;
        }
        u64 tot = myv + add1;
        u64 inc = tot;
        #pragma unroll
        for (int off = 1; off < 64; off <<= 1) {
            u64 n = __shfl_up(inc, off, 64);
            if (lane >= off) inc += n;
        }
        if (lane == 63) wScr64[wv] = inc;
        __syncthreads();
        if (t < 16) {
            u64 v = wScr64[t], inc2 = v;
            #pragma unroll
            for (int off = 1; off < 16; off <<= 1) {
                u64 n = __shfl_up(inc2, off, 64);
                if (t >= off) inc2 += n;
            }
            wScr64[t] = inc2 - v;
            if (t == 15) sTot = inc2;
        }
        __syncthreads();
        u64 excl = wScr64[wv] + inc - tot;
        int nBg0v = (int)(sTot >> 48);
        int bgS = (int)(excl >> 48);
        int prS = (int)((excl >> 32) & 0xFFFF);
        int evS = (int)((excl >> 16) & 0xFFFF);
        int ocS = (int)(excl & 0xFFFF);
        int start0 = pr0 ? (nBg0v + prS) : bgS;
        bEnd[t] = start0;
        occA[t] = ocS;
        evAx[t] = (unsigned short)evS;
        if (t >= 1) bSt[t - 1] = (unsigned short)start0;
        if (t == 1023) {
            u64 ex1 = excl + myv;
            int bgS1 = (int)(ex1 >> 48);
            int prS1 = (int)((ex1 >> 32) & 0xFFFF);
            int start1 = pr1 ? (nBg0v + prS1) : bgS1;
            bEnd[1024] = start1; occA[1024] = (int)(ex1 & 0xFFFF);
            bSt[1023] = (unsigned short)start1;
        }
    }
    __syncthreads();
    const int nBg0  = (int)(sTot >> 48);
    const int totEv = (int)((sTot >> 16) & 0xFFFF);
    const int EVcap = min(EVPOOL_CAP, PPTS - nBg0);

    // ---- D: scatter coords+ids; bg0 entries register grid cell here ----
    #pragma unroll
    for (int i = 0; i < 4; i++) {
        int p = t + (i << 10);
        int slot = atomicAdd(&bEnd[lab[i]], 1);
        ldsEnt[slot] = (unsigned short)p;
        bucketC[slot] = up[i];
        if (!((present[lab[i] >> 5] >> (lab[i] & 31)) & 1u)) {
            // bg0 entry (slot < nBg0): cell known now, count for grid
            int cx = min(31, max(0, (int)__fmul_rn(up[i].x, 32.0f)));
            int cy = min(31, max(0, (int)__fmul_rn(up[i].y, 32.0f)));
            int cell = (cx << 5) | cy;
            cellOf[slot] = (unsigned short)cell;
            atomicAdd(&cellCnt[cell], 1u);
        }
    }
    {
        int slot = atomicAdd(&occA[k1], 1);
        occList[slot] = (unsigned short)t;
    }
    __syncthreads();

    // ---- 1a: per-label inside-match chains (register-resident buckets) ----
    float costPartial = 0.0f;
    {
        const int l = t + 1;
        const int os = occA[t], oe = occA[l];
        for (int i = os + 1; i < oe; i++) {          // sort occurrences ascending
            unsigned short v = occList[i];
            int k = i - 1;
            while (k >= os && occList[k] > v) { occList[k + 1] = occList[k]; k--; }
            occList[k + 1] = v;
        }
        const int bs = bSt[t], be = bEnd[l];
        const int bn = be - bs;
        if (oe > os && bn > 0 && bn <= RB) {
            // fast path: bucket in registers, argmin is pure predicated VALU
            float rcx[RB], rcy[RB]; int rp[RB];
            #pragma unroll
            for (int k = 0; k < RB; k++)
                if (k < bn) { float2 c = bucketC[bs + k]; rcx[k] = c.x; rcy[k] = c.y;
                              rp[k] = ldsEnt[bs + k]; }
            unsigned cons = 0;
            for (int o = os; o < oe; o++) {
                int j = occList[o];
                float2 v = vLds[j];
                u64 best = ~0ull;
                #pragma unroll
                for (int k = 0; k < RB; k++) {
                    if (k < bn && !((cons >> k) & 1u)) {
                        float d2 = pdist2(v.x, v.y, rcx[k], rcy[k]);
                        u64 pk = ((u64)__float_as_uint(d2) << 24)
                                 | ((u64)(unsigned)rp[k] << 12) | (u64)(unsigned)k;
                        if (pk < best) best = pk;
                    }
                }
                if (best != ~0ull) {
                    int eW = (int)(best & 0xFFFull);
                    matchU[j] = (short)((best >> 12) & 0xFFFull);
                    costPartial = __fadd_rn(costPartial,
                        __fsqrt_rn(__uint_as_float((unsigned)(best >> 24))));
                    cons |= 1u << eW;
                    if (o == os) {                    // first occurrence: emit dumps
                        int base = evAx[j];
                        #pragma unroll
                        for (int k = 0; k < RB; k++) {
                            if (k < bn && k != eW) {
                                int idx = base + k - (k > eW ? 1 : 0);
                                if (idx < EVcap) evPool[idx] = (unsigned short)(bs + k);
                                else if (idx - EVcap < spillCap)
                                    evSpillB[idx - EVcap] = (unsigned short)rp[k];
                            }
                        }
                    }
                } else matchU[j] = -2;
            }
        } else if (oe > os) {
            // generic path: big buckets (rare) or empty bucket
            u64 cons = 0;
            for (int o = os; o < oe; o++) {
                int j = occList[o];
                float2 v = vLds[j];
                u64 best = ~0ull;
                int avail = 0;
                for (int e = bs; e < be; e++) {
                    int eIdx = e - bs;
                    int p = ldsEnt[e];
                    bool consd;
                    if (eIdx < 64) consd = (cons >> eIdx) & 1ull;
                    else {
                        consd = false;
                        for (int o2 = os; o2 < o; o2++)
                            if ((int)matchU[occList[o2]] == p) { consd = true; break; }
                    }
                    if (consd) continue;
                    avail++;
                    float2 u = bucketC[e];
                    float d2 = pdist2(v.x, v.y, u.x, u.y);
                    u64 pk = ((u64)__float_as_uint(d2) << 24) | ((u64)(unsigned)p << 12)
                             | (u64)(unsigned)eIdx;
                    if (pk < best) best = pk;
                }
                if (avail > 0) {
                    int eW = (int)(best & 0xFFFull);
                    matchU[j] = (short)((best >> 12) & 0xFFFull);
                    costPartial = __fadd_rn(costPartial,
                        __fsqrt_rn(__uint_as_float((unsigned)(best >> 24))));
                    if (eW < 64) cons |= 1ull << eW;
                    if (o == os) {
                        int base = evAx[j], w3 = 0;
                        for (int e = bs; e < be; e++) {
                            if (e - bs == eW) continue;
                            int idx = base + w3;
                            if (idx < EVcap) evPool[idx] = (unsigned short)e;
                            else if (idx - EVcap < spillCap)
                                evSpillB[idx - EVcap] = ldsEnt[e];
                            w3++;
                        }
                    }
                } else matchU[j] = -2;
            }
        }
    }
    __syncthreads();

    // ---- bg-step list compaction (ascending j); vSteps from registers ----
    int myRank;
    bool need;
    {
        need = (matchU[t] == (short)-2);
        u64 m = __ballot(need);
        myRank = need ? __popcll(m & ((1ull << lane) - 1ull)) : 0;
        if (lane == 0) wScrI[wv] = __popcll(m);
    }
    __syncthreads();
    if (t < 64) {
        int orig = (t < 16) ? wScrI[t] : 0;
        int v = orig;
        #pragma unroll
        for (int off = 1; off <= 8; off <<= 1) {
            int n = __shfl_up(v, off, 64);
            if (t >= off) v += n;
        }
        if (t < 16) wScrI[t] = v - orig;
        if (t == 15) scal[0] = v;
    }
    __syncthreads();
    if (need) {
        int idx = wScrI[wv] + myRank;
        if (idx < BGCAP) { bgListSh[idx] = (unsigned short)t; vSteps[idx] = vMe; }
    }
    __syncthreads();

    // ---- staging: event slots -> contiguous pool; register grid cells ----
    const int bgCnt = min(scal[0], BGCAP);
    {
        const int nStage = min(totEv, EVcap);
        float2 sc[4]; unsigned short sp[4];
        #pragma unroll
        for (int k = 0; k < 4; k++) {
            int i = t + (k << 10);
            if (i < nStage) { int slot = evPool[i]; sp[k] = ldsEnt[slot]; sc[k] = bucketC[slot]; }
        }
        __syncthreads();
        #pragma unroll
        for (int k = 0; k < 4; k++) {
            int i = t + (k << 10);
            if (i < nStage) {
                ldsEnt[nBg0 + i] = sp[k]; bucketC[nBg0 + i] = sc[k];
                int cx = min(31, max(0, (int)__fmul_rn(sc[k].x, 32.0f)));
                int cy = min(31, max(0, (int)__fmul_rn(sc[k].y, 32.0f)));
                int cell = (cx << 5) | cy;
                cellOf[nBg0 + i] = (unsigned short)cell;
                atomicAdd(&cellCnt[cell], 1u);
            }
        }
    }
    __syncthreads();

    // ---- beta: grid scan+scatter (counts pre-fused) + ring search ----
    if (bgCnt > 0) {
        const int nT = nBg0 + min(totEv, EVcap);   // total LDS-resident entries
        // exclusive scan of 1024 cell counts
        {
            unsigned c0 = cellCnt[t];
            unsigned inc = c0;
            #pragma unroll
            for (int off = 1; off < 64; off <<= 1) {
                unsigned n = __shfl_up(inc, off, 64);
                if (lane >= off) inc += n;
            }
            if (lane == 63) wScrI[wv] = (int)inc;
            __syncthreads();
            if (t < 16) {
                int v = wScrI[t], inc2 = v;
                #pragma unroll
                for (int off = 1; off < 16; off <<= 1) {
                    int n = __shfl_up(inc2, off, 64);
                    if (t >= off) inc2 += n;
                }
                wScrI[t] = inc2 - v;
            }
            __syncthreads();
            unsigned excl = (unsigned)wScrI[wv] + inc - c0;
            cellCnt[t] = excl;
            __syncthreads();
        }
        // scatter (after: cellCnt[c] == end[c]; start[c] = c? cellCnt[c-1] : 0)
        #pragma unroll
        for (int k = 0; k < 4; k++) {
            int i = t + (k << 10);
            if (i < nT) {
                int cell = cellOf[i];
                int slot = (int)atomicAdd(&cellCnt[cell], 1u);
                gIdx[slot] = (unsigned short)i;
                gP[slot]   = ldsEnt[i];
                gC[slot]   = bucketC[i];
            }
        }
        __syncthreads();
        // ring search: one step per wave; fused radius<=2 block, then rings
        for (int s = wv; s < bgCnt; s += 16) {
            const int js = bgListSh[s];
            const float2 v = vSteps[s];
            const int lim = nBg0 + min((int)evAx[js], EVcap);
            const int cx = min(31, max(0, (int)__fmul_rn(v.x, 32.0f)));
            const int cy = min(31, max(0, (int)__fmul_rn(v.y, 32.0f)));
            u64 best = ~0ull;                        // (d2<<32)|p
            // fused block: all 25 cells with Chebyshev radius <= 2, one reduce
            if (lane < 25) {
                int x = cx + (lane / 5) - 2, y = cy + (lane % 5) - 2;
                if ((unsigned)x < 32u && (unsigned)y < 32u) {
                    int c = (x << 5) | y;
                    int beg = c ? (int)cellCnt[c - 1] : 0;
                    int end = (int)cellCnt[c];
                    for (int i2 = beg; i2 < end; i2++) {
                        if (gIdx[i2] < lim) {
                            float2 cc = gC[i2];
                            float d2 = pdist2(v.x, v.y, cc.x, cc.y);
                            u64 pk = ((u64)__float_as_uint(d2) << 32) | gP[i2];
                            if (pk < best) best = pk;
                        }
                    }
                }
            }
            #pragma unroll
            for (int off = 32; off >= 1; off >>= 1) {
                u64 o = __shfl_xor(best, off, 64);
                if (o < best) best = o;
            }
            // remaining rings (rare): exact same bound/tiebreak as before
            for (int r = 3; r <= 31; r++) {
                // rings >= r are at Euclid dist >= (r-1)/32 (minus ulp slack)
                float gap = __fmul_rn((float)(r - 1), 0.03125f) - 1e-6f;
                float bd2 = __uint_as_float((unsigned)(best >> 32));
                if (bd2 < __fmul_rn(gap, gap)) break;    // NaN (no cand) -> continue
                const int ncells = 8 * r;
                for (int ci = lane; ci < ncells; ci += 64) {
                    int dx, dy;
                    if (ci < 2 * r)           { dx = -r + ci;            dy = -r; }
                    else if (ci < 4 * r)      { dx = r;                  dy = -r + (ci - 2 * r); }
                    else if (ci < 6 * r)      { dx = r - (ci - 4 * r);   dy = r; }
                    else                      { dx = -r;                 dy = r - (ci - 6 * r); }
                    int x = cx + dx, y = cy + dy;
                    if ((unsigned)x < 32u && (unsigned)y < 32u) {
                        int c = (x << 5) | y;
                        int beg = c ? (int)cellCnt[c - 1] : 0;
                        int end = (int)cellCnt[c];
                        for (int i2 = beg; i2 < end; i2++) {
                            if (gIdx[i2] < lim) {
                                float2 cc = gC[i2];
                                float d2 = pdist2(v.x, v.y, cc.x, cc.y);
                                u64 pk = ((u64)__float_as_uint(d2) << 32) | gP[i2];
                                if (pk < best) best = pk;
                            }
                        }
                    }
                }
                #pragma unroll
                for (int off = 32; off >= 1; off >>= 1) {
                    u64 o = __shfl_xor(best, off, 64);
                    if (o < best) best = o;
                }
            }
            // spill tail (idx >= EVcap; never in grid) — rare
            const int ne = evAx[js];
            if (ne > EVcap && spillCap > 0) {
                for (int ei = EVcap + lane; ei < ne; ei += 64) {
                    if (ei - EVcap >= spillCap) break;
                    unsigned p = evSpillB[ei - EVcap];
                    float2 c = Ub2[p];
                    float d2 = pdist2(v.x, v.y, c.x, c.y);
                    u64 pk = ((u64)__float_as_uint(d2) << 32) | p;
                    if (pk < best) best = pk;
                }
                #pragma unroll
                for (int off = 32; off >= 1; off >>= 1) {
                    u64 o = __shfl_xor(best, off, 64);
                    if (o < best) best = o;
                }
            }
            if (lane == 0) specWin[s] = best;        // specWin aliases dead bEnd
        }
    }
    __syncthreads();

    // ---- 2c': iterative parallel commit-and-fix ----
    // Invariant: a speculative winner (argmin over the full pre-consumption
    // prefix) is exact iff its point is unconsumed. Each round: find the
    // EARLIEST step whose winner is consumed-or-duplicated, commit everything
    // before it into the consumed bitmap (bgbits), recompute that one step
    // exactly with all 1024 threads. Rounds = 1 + #invalid winners.
    {
        int done = 0;
        for (;;) {
            if (t == 0) scal[3] = bgCnt;
            __syncthreads();
            if (t >= done && t < bgCnt) {
                u64 w = specWin[t];
                if (w != ~0ull) {
                    unsigned p = (unsigned)(w & 0xFFFFFFFFull);
                    bool inval = (bgbits[p >> 5] >> (p & 31)) & 1u;   // prior rounds
                    if (!inval) {
                        for (int s2 = done; s2 < t; s2++) {           // this window
                            u64 w2 = specWin[s2];
                            if (w2 != ~0ull &&
                                (unsigned)(w2 & 0xFFFFFFFFull) == p) { inval = true; break; }
                        }
                    }
                    if (inval) atomicMin(&scal[3], t);
                }
            }
            __syncthreads();
            const int fs = scal[3];
            if (fs >= bgCnt) break;                   // all remaining winners exact
            // commit winners of [done, fs) into consumed bitmap
            if (t >= done && t < fs) {
                u64 w = specWin[t];
                if (w != ~0ull) {
                    unsigned p = (unsigned)(w & 0xFFFFFFFFull);
                    atomicOr(&bgbits[p >> 5], 1u << (p & 31));
                }
            }
            __syncthreads();
            // exact recompute of step fs over its event-prefix, excluding consumed
            {
                const int js = bgListSh[fs];
                const float2 v = vSteps[fs];
                const int ne = evAx[js];
                const int lim = nBg0 + min(ne, EVcap);
                u64 best = ~0ull;
                for (int i = t; i < lim; i += 1024) {
                    unsigned p = ldsEnt[i];
                    if (!((bgbits[p >> 5] >> (p & 31)) & 1u)) {
                        float2 c = bucketC[i];
                        float d2 = pdist2(v.x, v.y, c.x, c.y);
                        u64 pk = ((u64)__float_as_uint(d2) << 32) | p;
                        if (pk < best) best = pk;
                    }
                }
                for (int ei = EVcap + t; ei < ne; ei += 1024) {       // spill tail (rare)
                    if (ei - EVcap >= spillCap) break;
                    unsigned p = evSpillB[ei - EVcap];
                    if (!((bgbits[p >> 5] >> (p & 31)) & 1u)) {
                        float2 c = Ub2[p];
                        float d2 = pdist2(v.x, v.y, c.x, c.y);
                        u64 pk = ((u64)__float_as_uint(d2) << 32) | p;
                        if (pk < best) best = pk;
                    }
                }
                #pragma unroll
                for (int off = 32; off >= 1; off >>= 1) {
                    u64 o = __shfl_xor(best, off, 64);
                    if (o < best) best = o;
                }
                if (lane == 0) wScr64[wv] = best;
                __syncthreads();
                if (t == 0) {
                    u64 bb = wScr64[0];
                    for (int i = 1; i < 16; i++) if (wScr64[i] < bb) bb = wScr64[i];
                    specWin[fs] = bb;                 // fixed winner (or ~0 = no cand)
                    if (bb != ~0ull) {
                        unsigned p = (unsigned)(bb & 0xFFFFFFFFull);
                        bgbits[p >> 5] |= 1u << (p & 31);
                    }
                }
                // loop-top __syncthreads orders t0's writes before next detection
            }
            done = fs + 1;
        }
    }
    // winners final; write matches + accumulate costs (sqrt on winners only)
    if (t < bgCnt) {
        const int js = bgListSh[t];
        u64 w0 = specWin[t];
        if (w0 == ~0ull) matchU[js] = -1;
        else {
            matchU[js] = (short)(w0 & 0xFFFFFFFFull);
            costPartial = __fadd_rn(costPartial,
                __fsqrt_rn(__uint_as_float((unsigned)(w0 >> 32))));
        }
    }
    __syncthreads();

    // ---- epilogue: cost reduction + outputs ----
    {
        float cp = costPartial;
        #pragma unroll
        for (int off = 32; off >= 1; off >>= 1) cp += __shfl_xor(cp, off, 64);
        if (lane == 0) wScrF[wv] = cp;
    }
    __syncthreads();
    if (t == 0) {
        float tot = 0.0f;
        for (int i = 0; i < 16; ++i) tot = __fadd_rn(tot, wScrF[i]);
        out[(size_t)2 * B * NGT + b] = tot;
    }
    {
        int u = matchU[t];
        out[(size_t)b * NGT + t] = (float)u;
        out[(size_t)B * NGT + (size_t)b * NGT + t] = (u >= 0) ? (float)t : -1.0f;
    }
}

extern "C" void kernel_launch(void* const* d_in, const int* in_sizes, int n_in,
                              void* d_out, int out_size, void* d_ws, size_t ws_size,
                              hipStream_t stream) {
    const float* pred   = (const float*)d_in[0];
    const float* coords = (const float*)d_in[1];
    const int*   keys   = (const int*)d_in[2];
    const int*   masks  = (const int*)d_in[3];
    float* out = (float*)d_out;
    int B = in_sizes[2] / NGT;   // 8
    int spillCap = (ws_size >= (size_t)WS_NEED) ? SPILL_CAP : 0;
    unsigned short* spillP = (unsigned short*)d_ws;
    matcher_kernel<<<B, 1024, 0, stream>>>(pred, coords, keys, masks, out,
                                           spillP, spillCap, B);
}

// Round 7
// 104.487 us; speedup vs baseline: 1.0787x; 1.0787x over previous
//
#include <hip/hip_runtime.h>
#include <stdint.h>

// Problem constants: B=8, P=4096, N=1024, H=W=1024, labels 0..1024
#define PPTS 4096
#define NGT  1024
#define HH   1024
#define WW   1024
#define EVPOOL_CAP 3072   // LDS event-slot pool; first-dump events ~1900 < cap
#define BGCAP 160         // max bg steps (E[m] ~65)
#define RB 12             // register-bucket cap in 1a (12 = proven scratch-free; 16 spills)

// workspace layout: part u16[8][1025][8] (transposed partial hists -> uint4 row loads);
// labels u16[8][4096]; spill u16[8][2048]
#define PART_BYTES (8 * 8 * 1025 * 2)            // 131200
#define LAB_OFF    PART_BYTES
#define SPILL_OFF  (LAB_OFF + 8 * PPTS * 2)      // 196736
#define SPILL_CAP  2048
#define WS_NEED    (SPILL_OFF + 8 * SPILL_CAP * 2)

typedef unsigned long long u64;

// squared distance, add-form (NOT fma) to bit-match reference dx*dx + dy*dy;
// sqrt is applied once to WINNERS only (sqrt_rn is monotone -> same argmin).
__device__ __forceinline__ float pdist2(float vx, float vy, float ux, float uy) {
    float dx = __fsub_rn(vx, ux);
    float dy = __fsub_rn(vy, uy);
    return __fadd_rn(__fmul_rn(dx, dx), __fmul_rn(dy, dy));
}

// K1: 8 blocks per batch, 512 threads — labels (random mask gather) + LDS
// histogram written non-atomically to ws as per-sub-block partials (no memset).
// Layout transposed: part[b][label][sb] so matcher reads one uint4 per label.
// K1 exists to give the random gathers 64-block TLP (R6 showed inlining them
// into the 8-block matcher costs +9 us of exposed gather latency).
__global__ __launch_bounds__(512) void label_kernel(
    const float* __restrict__ pred, const int* __restrict__ masks,
    unsigned short* __restrict__ part, unsigned short* __restrict__ labs)
{
    __shared__ int lh[1025];
    const int blk = blockIdx.x, b = blk >> 3, sb = blk & 7;
    const int t = threadIdx.x;
    lh[t] = 0; lh[t + 512] = 0;
    if (t == 0) lh[1024] = 0;
    __syncthreads();
    const int p = (sb << 9) + t;
    float2 u = ((const float2*)(pred + (size_t)b * PPTS * 2))[p];
    int xi = (int)rintf(__fmul_rn(u.x, 1024.0f));   // rintf == jnp.round (half-even)
    int yi = (int)rintf(__fmul_rn(u.y, 1024.0f));
    xi = min(max(xi, 0), HH - 1);
    yi = min(max(yi, 0), WW - 1);
    int lab = (masks + (size_t)b * HH * WW)[xi * WW + yi];
    labs[(size_t)b * PPTS + p] = (unsigned short)lab;
    atomicAdd(&lh[lab], 1);
    __syncthreads();
    unsigned short* Pp = part + (size_t)b * 8200;
    Pp[t * 8 + sb] = (unsigned short)lh[t];
    Pp[(t + 512) * 8 + sb] = (unsigned short)lh[t + 512];
    if (t == 0) Pp[1024 * 8 + sb] = (unsigned short)lh[1024];
}

// K2: one block per batch — r12 structure + commit-and-fix 2c + grid beta.
// This round: revert to R5 two-kernel split + single-ballot compaction +
// O(1) owner-table duplicate detection in 2c' (owner aliases dead gC).
__global__ __launch_bounds__(1024) void matcher_kernel(
    const float* __restrict__ pred,    // [B,P,2]
    const float* __restrict__ coords,  // [B,N,2]
    const int*   __restrict__ keys,    // [B,N]
    const int*   __restrict__ masks,   // [B,H,W] (mono path only)
    float* __restrict__ out,           // [B*N src][B*N tgt][B total]
    const unsigned short* __restrict__ part, const unsigned short* __restrict__ labs,
    unsigned short* __restrict__ spill, int useWs, int B)
{
    __shared__ __align__(16) char regU[32768];          // bucketC f2[4096] (bg0 + staged ev)
    __shared__ __align__(8)  char regE[8192];           // ldsEnt u16[4096]
    __shared__ __align__(8)  char regB[8200];           // bEnd+occA -> specWin u64[BGCAP]
    __shared__ __align__(8)  char regP[2 * EVPOOL_CAP]; // firstOcc i32 -> evPool u16
    __shared__ __align__(4)  char regS[384];            // present u32[33] -> bgListSh u16[BGCAP]
    __shared__ __align__(8)  char regT[2048];           // bSt u16[1024] -> vSteps f2[BGCAP]
    __shared__ u64            wScr64[16];
    __shared__ u64            sTot;
    __shared__ unsigned short evAx[1024];
    __shared__ unsigned short occList[NGT];
    __shared__ short          matchU[NGT];
    __shared__ unsigned       bgbits[PPTS / 32];        // consumed-winner bitmap
    __shared__ int            scal[4];                  // 0:bgCnt 3:earliest-invalid
    __shared__ float2         vLds[NGT];                // V staged in LDS (1a gathers)
    // spatial grid (beta): 32x32 cells over [0,1]^2 — dedicated storage
    __shared__ unsigned       cellCnt[1024];            // counts -> excl scan -> ends
    __shared__ unsigned short cellOf[PPTS];             // cell of staged entry i
    __shared__ unsigned short gIdx[PPTS];               // staged-entry index (prefix filter)
    __shared__ unsigned short gP[PPTS];                 // point id
    __shared__ __align__(16) float2 gC[PPTS];           // coords -> owner i32[4096] in 2c'

    float2*         bucketC  = (float2*)regU;
    unsigned short* ldsEnt   = (unsigned short*)regE;
    int*            bEnd     = (int*)regB;
    int*            occA     = ((int*)regB) + 1025;
    u64*            specWin  = (u64*)regB;
    int*            firstOcc = (int*)regP;
    unsigned short* evPool   = (unsigned short*)regP;
    unsigned*       present  = (unsigned*)regS;
    unsigned short* bgListSh = (unsigned short*)regS;
    unsigned short* bSt      = (unsigned short*)regT;   // dead after 1a
    float2*         vSteps   = (float2*)regT;           // alias: written at compaction
    int*            owner    = (int*)gC;                // alias: gC dead after beta
    int*   wScrI = (int*)wScr64;
    float* wScrF = (float*)wScr64;

    const int b = blockIdx.x;
    const int t = threadIdx.x;
    const int lane = t & 63, wv = t >> 6;
    const float* Ub = pred   + (size_t)b * PPTS * 2;
    const float2* Ub2 = (const float2*)Ub;
    const float* Vb = coords + (size_t)b * NGT * 2;
    const float2* Vb2 = (const float2*)Vb;
    const int*   Kb = keys   + (size_t)b * NGT;
    unsigned short* evSpillB = spill + (size_t)b * SPILL_CAP;
    const int spillCap = useWs ? SPILL_CAP : 0;

    // ---- A/B: init + bucket counts + key-side stats (LDS atomics) ----
    if (t < PPTS / 32) bgbits[t] = 0;
    if (t == 0) scal[0] = 0;
    cellCnt[t] = 0;                              // grid counts (filled at D/staging)
    const int k1 = Kb[t] + 1;                    // label of step j=t, in [1,1024]
    const float2 vMe = Vb2[t];                   // coalesced; reused for vSteps
    vLds[t] = vMe;                               // stage V in LDS for 1a gathers
    int lab[4]; float2 up[4];
    #pragma unroll
    for (int i = 0; i < 4; i++) up[i] = Ub2[t + (i << 10)];
    occA[t] = 0; firstOcc[t] = 0x7FFFFFFF;
    if (t == 0) { occA[1024] = 0; firstOcc[1024] = 0x7FFFFFFF; }
    if (t < 33) present[t] = 0;
    if (useWs) {
        const unsigned short* Pb = part + (size_t)b * 8200;
        const uint4 pv = reinterpret_cast<const uint4*>(Pb)[t];   // 8 sub-hists, 16B
        int s = (int)(pv.x & 0xFFFFu) + (int)(pv.x >> 16)
              + (int)(pv.y & 0xFFFFu) + (int)(pv.y >> 16)
              + (int)(pv.z & 0xFFFFu) + (int)(pv.z >> 16)
              + (int)(pv.w & 0xFFFFu) + (int)(pv.w >> 16);
        bEnd[t] = s;
        if (t == 0) {
            const uint4 p1 = reinterpret_cast<const uint4*>(Pb)[1024];
            bEnd[1024] = (int)(p1.x & 0xFFFFu) + (int)(p1.x >> 16)
                       + (int)(p1.y & 0xFFFFu) + (int)(p1.y >> 16)
                       + (int)(p1.z & 0xFFFFu) + (int)(p1.z >> 16)
                       + (int)(p1.w & 0xFFFFu) + (int)(p1.w >> 16);
        }
        const unsigned short* Lb = labs + (size_t)b * PPTS;
        #pragma unroll
        for (int i = 0; i < 4; i++) lab[i] = Lb[t + (i << 10)];
    } else {
        bEnd[t] = 0;
        if (t == 0) bEnd[1024] = 0;
    }
    __syncthreads();
    atomicOr(&present[k1 >> 5], 1u << (k1 & 31));
    atomicAdd(&occA[k1], 1);
    atomicMin(&firstOcc[k1], t);
    if (!useWs) {
        const int* Mb = masks + (size_t)b * HH * WW;
        #pragma unroll
        for (int i = 0; i < 4; i++) {
            float2 u = up[i];
            int xi = (int)rintf(__fmul_rn(u.x, 1024.0f));
            int yi = (int)rintf(__fmul_rn(u.y, 1024.0f));
            xi = min(max(xi, 0), HH - 1);
            yi = min(max(yi, 0), WW - 1);
            lab[i] = Mb[xi * WW + yi];
            atomicAdd(&bEnd[lab[i]], 1);
        }
    }
    __syncthreads();

    // ---- C: quad-packed exclusive scan (bg<<48 | pr<<32 | ev<<16 | occ) ----
    {
        int c0 = bEnd[t], o0 = occA[t];
        bool pr0 = (present[t >> 5] >> (t & 31)) & 1u;
        int bCnt = bEnd[k1];
        int fo   = firstOcc[k1];
        int evc  = (fo == t && bCnt > 0) ? (bCnt - 1) : 0;
        u64 myv = (pr0 ? ((u64)(unsigned)c0 << 32) : ((u64)(unsigned)c0 << 48))
                  | ((u64)(unsigned)evc << 16) | (u64)(unsigned)o0;
        u64 add1 = 0; bool pr1 = false;
        if (t == 1023) {                          // fold label 1024 (no step 1024)
            int c1 = bEnd[1024], o1 = occA[1024];
            pr1 = present[32] & 1u;
            add1 = (pr1 ? ((u64)(unsigned)c1 << 32) : ((u64)(unsigned)c1 << 48))
                   | (u64)(unsigned)o1;
        }
        u64 tot = myv + add1;
        u64 inc = tot;
        #pragma unroll
        for (int off = 1; off < 64; off <<= 1) {
            u64 n = __shfl_up(inc, off, 64);
            if (lane >= off) inc += n;
        }
        if (lane == 63) wScr64[wv] = inc;
        __syncthreads();
        if (t < 16) {
            u64 v = wScr64[t], inc2 = v;
            #pragma unroll
            for (int off = 1; off < 16; off <<= 1) {
                u64 n = __shfl_up(inc2, off, 64);
                if (t >= off) inc2 += n;
            }
            wScr64[t] = inc2 - v;
            if (t == 15) sTot = inc2;
        }
        __syncthreads();
        u64 excl = wScr64[wv] + inc - tot;
        int nBg0v = (int)(sTot >> 48);
        int bgS = (int)(excl >> 48);
        int prS = (int)((excl >> 32) & 0xFFFF);
        int evS = (int)((excl >> 16) & 0xFFFF);
        int ocS = (int)(excl & 0xFFFF);
        int start0 = pr0 ? (nBg0v + prS) : bgS;
        bEnd[t] = start0;
        occA[t] = ocS;
        evAx[t] = (unsigned short)evS;
        if (t >= 1) bSt[t - 1] = (unsigned short)start0;
        if (t == 1023) {
            u64 ex1 = excl + myv;
            int bgS1 = (int)(ex1 >> 48);
            int prS1 = (int)((ex1 >> 32) & 0xFFFF);
            int start1 = pr1 ? (nBg0v + prS1) : bgS1;
            bEnd[1024] = start1; occA[1024] = (int)(ex1 & 0xFFFF);
            bSt[1023] = (unsigned short)start1;
        }
    }
    __syncthreads();
    const int nBg0  = (int)(sTot >> 48);
    const int totEv = (int)((sTot >> 16) & 0xFFFF);
    const int EVcap = min(EVPOOL_CAP, PPTS - nBg0);

    // ---- D: scatter coords+ids; bg0 entries register grid cell here ----
    #pragma unroll
    for (int i = 0; i < 4; i++) {
        int p = t + (i << 10);
        int slot = atomicAdd(&bEnd[lab[i]], 1);
        ldsEnt[slot] = (unsigned short)p;
        bucketC[slot] = up[i];
        if (!((present[lab[i] >> 5] >> (lab[i] & 31)) & 1u)) {
            // bg0 entry (slot < nBg0): cell known now, count for grid
            int cx = min(31, max(0, (int)__fmul_rn(up[i].x, 32.0f)));
            int cy = min(31, max(0, (int)__fmul_rn(up[i].y, 32.0f)));
            int cell = (cx << 5) | cy;
            cellOf[slot] = (unsigned short)cell;
            atomicAdd(&cellCnt[cell], 1u);
        }
    }
    {
        int slot = atomicAdd(&occA[k1], 1);
        occList[slot] = (unsigned short)t;
    }
    __syncthreads();

    // ---- 1a: per-label inside-match chains (register-resident buckets) ----
    float costPartial = 0.0f;
    {
        const int l = t + 1;
        const int os = occA[t], oe = occA[l];
        for (int i = os + 1; i < oe; i++) {          // sort occurrences ascending
            unsigned short v = occList[i];
            int k = i - 1;
            while (k >= os && occList[k] > v) { occList[k + 1] = occList[k]; k--; }
            occList[k + 1] = v;
        }
        const int bs = bSt[t], be = bEnd[l];
        const int bn = be - bs;
        if (oe > os && bn > 0 && bn <= RB) {
            // fast path: bucket in registers, argmin is pure predicated VALU
            float rcx[RB], rcy[RB]; int rp[RB];
            #pragma unroll
            for (int k = 0; k < RB; k++)
                if (k < bn) { float2 c = bucketC[bs + k]; rcx[k] = c.x; rcy[k] = c.y;
                              rp[k] = ldsEnt[bs + k]; }
            unsigned cons = 0;
            for (int o = os; o < oe; o++) {
                int j = occList[o];
                float2 v = vLds[j];
                u64 best = ~0ull;
                #pragma unroll
                for (int k = 0; k < RB; k++) {
                    if (k < bn && !((cons >> k) & 1u)) {
                        float d2 = pdist2(v.x, v.y, rcx[k], rcy[k]);
                        u64 pk = ((u64)__float_as_uint(d2) << 24)
                                 | ((u64)(unsigned)rp[k] << 12) | (u64)(unsigned)k;
                        if (pk < best) best = pk;
                    }
                }
                if (best != ~0ull) {
                    int eW = (int)(best & 0xFFFull);
                    matchU[j] = (short)((best >> 12) & 0xFFFull);
                    costPartial = __fadd_rn(costPartial,
                        __fsqrt_rn(__uint_as_float((unsigned)(best >> 24))));
                    cons |= 1u << eW;
                    if (o == os) {                    // first occurrence: emit dumps
                        int base = evAx[j];
                        #pragma unroll
                        for (int k = 0; k < RB; k++) {
                            if (k < bn && k != eW) {
                                int idx = base + k - (k > eW ? 1 : 0);
                                if (idx < EVcap) evPool[idx] = (unsigned short)(bs + k);
                                else if (idx - EVcap < spillCap)
                                    evSpillB[idx - EVcap] = (unsigned short)rp[k];
                            }
                        }
                    }
                } else matchU[j] = -2;
            }
        } else if (oe > os) {
            // generic path: big buckets (rare) or empty bucket
            u64 cons = 0;
            for (int o = os; o < oe; o++) {
                int j = occList[o];
                float2 v = vLds[j];
                u64 best = ~0ull;
                int avail = 0;
                for (int e = bs; e < be; e++) {
                    int eIdx = e - bs;
                    int p = ldsEnt[e];
                    bool consd;
                    if (eIdx < 64) consd = (cons >> eIdx) & 1ull;
                    else {
                        consd = false;
                        for (int o2 = os; o2 < o; o2++)
                            if ((int)matchU[occList[o2]] == p) { consd = true; break; }
                    }
                    if (consd) continue;
                    avail++;
                    float2 u = bucketC[e];
                    float d2 = pdist2(v.x, v.y, u.x, u.y);
                    u64 pk = ((u64)__float_as_uint(d2) << 24) | ((u64)(unsigned)p << 12)
                             | (u64)(unsigned)eIdx;
                    if (pk < best) best = pk;
                }
                if (avail > 0) {
                    int eW = (int)(best & 0xFFFull);
                    matchU[j] = (short)((best >> 12) & 0xFFFull);
                    costPartial = __fadd_rn(costPartial,
                        __fsqrt_rn(__uint_as_float((unsigned)(best >> 24))));
                    if (eW < 64) cons |= 1ull << eW;
                    if (o == os) {
                        int base = evAx[j], w3 = 0;
                        for (int e = bs; e < be; e++) {
                            if (e - bs == eW) continue;
                            int idx = base + w3;
                            if (idx < EVcap) evPool[idx] = (unsigned short)e;
                            else if (idx - EVcap < spillCap)
                                evSpillB[idx - EVcap] = ldsEnt[e];
                            w3++;
                        }
                    }
                } else matchU[j] = -2;
            }
        }
    }
    __syncthreads();

    // ---- bg-step list compaction (ascending j); vSteps from registers ----
    int myRank;
    bool need;
    {
        need = (matchU[t] == (short)-2);
        u64 m = __ballot(need);
        myRank = need ? __popcll(m & ((1ull << lane) - 1ull)) : 0;
        if (lane == 0) wScrI[wv] = __popcll(m);
    }
    __syncthreads();
    if (t < 64) {
        int orig = (t < 16) ? wScrI[t] : 0;
        int v = orig;
        #pragma unroll
        for (int off = 1; off <= 8; off <<= 1) {
            int n = __shfl_up(v, off, 64);
            if (t >= off) v += n;
        }
        if (t < 16) wScrI[t] = v - orig;
        if (t == 15) scal[0] = v;
    }
    __syncthreads();
    if (need) {
        int idx = wScrI[wv] + myRank;
        if (idx < BGCAP) { bgListSh[idx] = (unsigned short)t; vSteps[idx] = vMe; }
    }
    __syncthreads();

    // ---- staging: event slots -> contiguous pool; register grid cells ----
    const int bgCnt = min(scal[0], BGCAP);
    {
        const int nStage = min(totEv, EVcap);
        float2 sc[4]; unsigned short sp[4];
        #pragma unroll
        for (int k = 0; k < 4; k++) {
            int i = t + (k << 10);
            if (i < nStage) { int slot = evPool[i]; sp[k] = ldsEnt[slot]; sc[k] = bucketC[slot]; }
        }
        __syncthreads();
        #pragma unroll
        for (int k = 0; k < 4; k++) {
            int i = t + (k << 10);
            if (i < nStage) {
                ldsEnt[nBg0 + i] = sp[k]; bucketC[nBg0 + i] = sc[k];
                int cx = min(31, max(0, (int)__fmul_rn(sc[k].x, 32.0f)));
                int cy = min(31, max(0, (int)__fmul_rn(sc[k].y, 32.0f)));
                int cell = (cx << 5) | cy;
                cellOf[nBg0 + i] = (unsigned short)cell;
                atomicAdd(&cellCnt[cell], 1u);
            }
        }
    }
    __syncthreads();

    // ---- beta: grid scan+scatter (counts pre-fused) + ring search ----
    if (bgCnt > 0) {
        const int nT = nBg0 + min(totEv, EVcap);   // total LDS-resident entries
        // exclusive scan of 1024 cell counts
        {
            unsigned c0 = cellCnt[t];
            unsigned inc = c0;
            #pragma unroll
            for (int off = 1; off < 64; off <<= 1) {
                unsigned n = __shfl_up(inc, off, 64);
                if (lane >= off) inc += n;
            }
            if (lane == 63) wScrI[wv] = (int)inc;
            __syncthreads();
            if (t < 16) {
                int v = wScrI[t], inc2 = v;
                #pragma unroll
                for (int off = 1; off < 16; off <<= 1) {
                    int n = __shfl_up(inc2, off, 64);
                    if (t >= off) inc2 += n;
                }
                wScrI[t] = inc2 - v;
            }
            __syncthreads();
            unsigned excl = (unsigned)wScrI[wv] + inc - c0;
            cellCnt[t] = excl;
            __syncthreads();
        }
        // scatter (after: cellCnt[c] == end[c]; start[c] = c? cellCnt[c-1] : 0)
        #pragma unroll
        for (int k = 0; k < 4; k++) {
            int i = t + (k << 10);
            if (i < nT) {
                int cell = cellOf[i];
                int slot = (int)atomicAdd(&cellCnt[cell], 1u);
                gIdx[slot] = (unsigned short)i;
                gP[slot]   = ldsEnt[i];
                gC[slot]   = bucketC[i];
            }
        }
        __syncthreads();
        // ring search: one step per wave; fused radius<=2 block, then rings
        for (int s = wv; s < bgCnt; s += 16) {
            const int js = bgListSh[s];
            const float2 v = vSteps[s];
            const int lim = nBg0 + min((int)evAx[js], EVcap);
            const int cx = min(31, max(0, (int)__fmul_rn(v.x, 32.0f)));
            const int cy = min(31, max(0, (int)__fmul_rn(v.y, 32.0f)));
            u64 best = ~0ull;                        // (d2<<32)|p
            // fused block: all 25 cells with Chebyshev radius <= 2, one reduce
            if (lane < 25) {
                int x = cx + (lane / 5) - 2, y = cy + (lane % 5) - 2;
                if ((unsigned)x < 32u && (unsigned)y < 32u) {
                    int c = (x << 5) | y;
                    int beg = c ? (int)cellCnt[c - 1] : 0;
                    int end = (int)cellCnt[c];
                    for (int i2 = beg; i2 < end; i2++) {
                        if (gIdx[i2] < lim) {
                            float2 cc = gC[i2];
                            float d2 = pdist2(v.x, v.y, cc.x, cc.y);
                            u64 pk = ((u64)__float_as_uint(d2) << 32) | gP[i2];
                            if (pk < best) best = pk;
                        }
                    }
                }
            }
            #pragma unroll
            for (int off = 32; off >= 1; off >>= 1) {
                u64 o = __shfl_xor(best, off, 64);
                if (o < best) best = o;
            }
            // remaining rings (rare): exact same bound/tiebreak as before
            for (int r = 3; r <= 31; r++) {
                // rings >= r are at Euclid dist >= (r-1)/32 (minus ulp slack)
                float gap = __fmul_rn((float)(r - 1), 0.03125f) - 1e-6f;
                float bd2 = __uint_as_float((unsigned)(best >> 32));
                if (bd2 < __fmul_rn(gap, gap)) break;    // NaN (no cand) -> continue
                const int ncells = 8 * r;
                for (int ci = lane; ci < ncells; ci += 64) {
                    int dx, dy;
                    if (ci < 2 * r)           { dx = -r + ci;            dy = -r; }
                    else if (ci < 4 * r)      { dx = r;                  dy = -r + (ci - 2 * r); }
                    else if (ci < 6 * r)      { dx = r - (ci - 4 * r);   dy = r; }
                    else                      { dx = -r;                 dy = r - (ci - 6 * r); }
                    int x = cx + dx, y = cy + dy;
                    if ((unsigned)x < 32u && (unsigned)y < 32u) {
                        int c = (x << 5) | y;
                        int beg = c ? (int)cellCnt[c - 1] : 0;
                        int end = (int)cellCnt[c];
                        for (int i2 = beg; i2 < end; i2++) {
                            if (gIdx[i2] < lim) {
                                float2 cc = gC[i2];
                                float d2 = pdist2(v.x, v.y, cc.x, cc.y);
                                u64 pk = ((u64)__float_as_uint(d2) << 32) | gP[i2];
                                if (pk < best) best = pk;
                            }
                        }
                    }
                }
                #pragma unroll
                for (int off = 32; off >= 1; off >>= 1) {
                    u64 o = __shfl_xor(best, off, 64);
                    if (o < best) best = o;
                }
            }
            // spill tail (idx >= EVcap; never in grid) — rare
            const int ne = evAx[js];
            if (ne > EVcap && spillCap > 0) {
                for (int ei = EVcap + lane; ei < ne; ei += 64) {
                    if (ei - EVcap >= spillCap) break;
                    unsigned p = evSpillB[ei - EVcap];
                    float2 c = Ub2[p];
                    float d2 = pdist2(v.x, v.y, c.x, c.y);
                    u64 pk = ((u64)__float_as_uint(d2) << 32) | p;
                    if (pk < best) best = pk;
                }
                #pragma unroll
                for (int off = 32; off >= 1; off >>= 1) {
                    u64 o = __shfl_xor(best, off, 64);
                    if (o < best) best = o;
                }
            }
            if (lane == 0) specWin[s] = best;        // specWin aliases dead bEnd
        }
    }
    __syncthreads();

    // ---- owner table init (gC dead after ring search) ----
    #pragma unroll
    for (int k = 0; k < 4; k++) owner[t + (k << 10)] = 0x7FFFFFFF;

    // ---- 2c': iterative parallel commit-and-fix, O(1) dup detection ----
    // Invariant: a speculative winner (argmin over the full pre-consumption
    // prefix) is exact iff its point is unconsumed. Each round: find the
    // EARLIEST step whose winner is consumed-or-duplicated (dup via
    // atomicMin owner table), commit everything before it into the consumed
    // bitmap (bgbits), recompute that one step exactly with all 1024 threads.
    // Stale owner entries from prior rounds can only hit threads whose winner
    // is already bgbits-consumed (prior claimants' winners are committed
    // before the next round), so the verdict is unchanged.
    {
        int done = 0;
        for (;;) {
            if (t == 0) scal[3] = bgCnt;
            __syncthreads();                      // also orders owner init/writes
            u64 w = ~0ull; unsigned p = 0; bool act = false;
            if (t >= done && t < bgCnt) {
                w = specWin[t];
                if (w != ~0ull) {
                    p = (unsigned)(w & 0xFFFFFFFFull);
                    act = true;
                    atomicMin(&owner[p], t);
                }
            }
            __syncthreads();
            if (act) {
                bool inval = ((bgbits[p >> 5] >> (p & 31)) & 1u) || (owner[p] < t);
                if (inval) atomicMin(&scal[3], t);
            }
            __syncthreads();
            const int fs = scal[3];
            if (fs >= bgCnt) break;                   // all remaining winners exact
            // commit winners of [done, fs) into consumed bitmap
            if (act && t < fs) {
                atomicOr(&bgbits[p >> 5], 1u << (p & 31));
            }
            __syncthreads();
            // exact recompute of step fs over its event-prefix, excluding consumed
            {
                const int js = bgListSh[fs];
                const float2 v = vSteps[fs];
                const int ne = evAx[js];
                const int lim = nBg0 + min(ne, EVcap);
                u64 best = ~0ull;
                for (int i = t; i < lim; i += 1024) {
                    unsigned pp = ldsEnt[i];
                    if (!((bgbits[pp >> 5] >> (pp & 31)) & 1u)) {
                        float2 c = bucketC[i];
                        float d2 = pdist2(v.x, v.y, c.x, c.y);
                        u64 pk = ((u64)__float_as_uint(d2) << 32) | pp;
                        if (pk < best) best = pk;
                    }
                }
                for (int ei = EVcap + t; ei < ne; ei += 1024) {       // spill tail (rare)
                    if (ei - EVcap >= spillCap) break;
                    unsigned pp = evSpillB[ei - EVcap];
                    if (!((bgbits[pp >> 5] >> (pp & 31)) & 1u)) {
                        float2 c = Ub2[pp];
                        float d2 = pdist2(v.x, v.y, c.x, c.y);
                        u64 pk = ((u64)__float_as_uint(d2) << 32) | pp;
                        if (pk < best) best = pk;
                    }
                }
                #pragma unroll
                for (int off = 32; off >= 1; off >>= 1) {
                    u64 o = __shfl_xor(best, off, 64);
                    if (o < best) best = o;
                }
                if (lane == 0) wScr64[wv] = best;
                __syncthreads();
                if (t == 0) {
                    u64 bb = wScr64[0];
                    for (int i = 1; i < 16; i++) if (wScr64[i] < bb) bb = wScr64[i];
                    specWin[fs] = bb;                 // fixed winner (or ~0 = no cand)
                    if (bb != ~0ull) {
                        unsigned pp = (unsigned)(bb & 0xFFFFFFFFull);
                        bgbits[pp >> 5] |= 1u << (pp & 31);
                    }
                }
                // loop-top __syncthreads orders t0's writes before next detection
            }
            done = fs + 1;
        }
    }
    // winners final; write matches + accumulate costs (sqrt on winners only)
    if (t < bgCnt) {
        const int js = bgListSh[t];
        u64 w0 = specWin[t];
        if (w0 == ~0ull) matchU[js] = -1;
        else {
            matchU[js] = (short)(w0 & 0xFFFFFFFFull);
            costPartial = __fadd_rn(costPartial,
                __fsqrt_rn(__uint_as_float((unsigned)(w0 >> 32))));
        }
    }
    __syncthreads();

    // ---- epilogue: cost reduction + outputs ----
    {
        float cp = costPartial;
        #pragma unroll
        for (int off = 32; off >= 1; off >>= 1) cp += __shfl_xor(cp, off, 64);
        if (lane == 0) wScrF[wv] = cp;
    }
    __syncthreads();
    if (t == 0) {
        float tot = 0.0f;
        for (int i = 0; i < 16; ++i) tot = __fadd_rn(tot, wScrF[i]);
        out[(size_t)2 * B * NGT + b] = tot;
    }
    {
        int u = matchU[t];
        out[(size_t)b * NGT + t] = (float)u;
        out[(size_t)B * NGT + (size_t)b * NGT + t] = (u >= 0) ? (float)t : -1.0f;
    }
}

extern "C" void kernel_launch(void* const* d_in, const int* in_sizes, int n_in,
                              void* d_out, int out_size, void* d_ws, size_t ws_size,
                              hipStream_t stream) {
    const float* pred   = (const float*)d_in[0];
    const float* coords = (const float*)d_in[1];
    const int*   keys   = (const int*)d_in[2];
    const int*   masks  = (const int*)d_in[3];
    float* out = (float*)d_out;
    int B = in_sizes[2] / NGT;   // 8
    int useWs = (B == 8 && ws_size >= (size_t)WS_NEED) ? 1 : 0;
    unsigned short* partP  = (unsigned short*)d_ws;
    unsigned short* labsP  = (unsigned short*)((char*)d_ws + LAB_OFF);
    unsigned short* spillP = (unsigned short*)((char*)d_ws + SPILL_OFF);
    if (useWs) {
        label_kernel<<<B * 8, 512, 0, stream>>>(pred, masks, partP, labsP);
    }
    matcher_kernel<<<B, 1024, 0, stream>>>(pred, coords, keys, masks, out,
                                           partP, labsP, spillP, useWs, B);
}